// Round 5
// baseline (419.502 us; speedup 1.0000x reference)
//
#include <hip/hip_runtime.h>
#include <math.h>
#include <stdint.h>

#define Bb   128
#define Nn   100
#define Ee   3200
#define NTOT (Bb*Nn)    // 12800
#define ETOT (Bb*Ee)    // 409600
#define NT   512        // threads per block (8 waves)

// One block per batch: CSR build, edge-MLP+segment-sum (LDS atomics),
// k/v projection, g1 attention (marked nodes only), g2 at agent node —
// all phases intra-block, separated by __syncthreads(). One launch total.

__device__ __forceinline__ void ln_reg(float* h, const float* __restrict__ g,
                                       const float* __restrict__ b) {
    float s = 0.f;
#pragma unroll
    for (int c = 0; c < 16; c++) s += h[c];
    float m = s * 0.0625f;
    float v = 0.f;
#pragma unroll
    for (int c = 0; c < 16; c++) { float d = h[c] - m; v += d * d; }
    float r = rsqrtf(v * 0.0625f + 1e-5f);
#pragma unroll
    for (int c = 0; c < 16; c++) h[c] = (h[c] - m) * r * g[c] + b[c];
}

__global__ __launch_bounds__(NT) void k_all(
    const float* __restrict__ nf, const int* __restrict__ ei,
    const float* __restrict__ ea, const int* __restrict__ agent,
    const float* __restrict__ ee,
    const float* __restrict__ W1, const float* __restrict__ b1,
    const float* __restrict__ W2, const float* __restrict__ b2,
    const float* __restrict__ W3, const float* __restrict__ b3,
    const float* __restrict__ lg, const float* __restrict__ lb,
    const float* __restrict__ Wq1, const float* __restrict__ bq1,
    const float* __restrict__ Wk1, const float* __restrict__ bk1,
    const float* __restrict__ Wv1, const float* __restrict__ bv1,
    const float* __restrict__ We1, const float* __restrict__ Ws1,
    const float* __restrict__ bs1,
    const float* __restrict__ Wq2, const float* __restrict__ bq2,
    const float* __restrict__ Wk2, const float* __restrict__ bk2,
    const float* __restrict__ Wv2, const float* __restrict__ bv2,
    const float* __restrict__ We2, const float* __restrict__ Ws2,
    const float* __restrict__ bs2,
    int2* __restrict__ cpair, float* __restrict__ k1, float* __restrict__ v1,
    float* __restrict__ out)
{
    __shared__ float zs[Nn * 17];     // z, padded stride 17 (bank-spread for atomics)
    __shared__ float a1s[Nn * 16];    // g1 output at marked nodes
    __shared__ int cnt[128], exc[128], cur[128];
    __shared__ int offl[Nn + 1];
    __shared__ int markf[Nn];
    __shared__ int list[Nn];
    __shared__ int nmark;
    __shared__ float sm[8][64], sl[8][64], sa0[8][64], sa1[8][64];

    int b = blockIdx.x;
    int t = threadIdx.x;
    int lane = t & 63;
    int w = t >> 6;
    const int* eis = ei + (size_t)b * 2 * Ee;   // src row (batch-local node ids)
    const int* eid = eis + Ee;                  // dst row

    // ---- init LDS ----
    for (int i = t; i < 128; i += NT) cnt[i] = 0;
    for (int i = t; i < Nn; i += NT) markf[i] = 0;
    for (int i = t; i < Nn * 17; i += NT) zs[i] = 0.f;
    if (t == 0) nmark = 0;
    __syncthreads();

    // ---- CSR: histogram ----
    for (int e = t; e < Ee; e += NT) atomicAdd(&cnt[eid[e]], 1);
    __syncthreads();
    // ---- scan (Hillis-Steele over 128, all threads hit the barriers) ----
    if (t < 128) exc[t] = cnt[t];
    __syncthreads();
    for (int d = 1; d < 128; d <<= 1) {
        int v = 0;
        if (t < 128 && t >= d) v = exc[t - d];
        __syncthreads();
        if (t < 128) exc[t] += v;
        __syncthreads();
    }
    if (t < 128) { int e0 = exc[t] - cnt[t]; exc[t] = e0; cur[t] = e0; }
    __syncthreads();
    if (t <= Nn) offl[t] = exc[t];      // exc[100] == Ee
    // ---- scatter + mark srcs of agent in-edges ----
    int an = agent[b];
    for (int e = t; e < Ee; e += NT) {
        int dst = eid[e], src = eis[e];
        int idx = atomicAdd(&cur[dst], 1);
        cpair[(size_t)b * Ee + idx] = make_int2(src, e);   // batch-local ids
        if (dst == an) markf[src] = 1;
    }
    if (t == 0) markf[an] = 1;
    __syncthreads();
    // ---- compact marked list (concurrent with MLP, consumed after barrier) ----
    if (t < Nn && markf[t]) { int i = atomicAdd(&nmark, 1); list[i] = t; }

    // ---- edge MLP (original edge order: coalesced ea) + LDS-atomic segment sum ----
    for (int e = t; e < Ee; e += NT) {
        int src = eis[e], dst = eid[e];
        int et = (int)nf[b * Nn + src];
        float in[12];
#pragma unroll
        for (int j = 0; j < 4; j++) in[j] = ee[et * 4 + j];
        const float4* ea4 = (const float4*)(ea + ((size_t)b * Ee + e) * 8);
        float4 ua = ea4[0], ub = ea4[1];
        in[4] = ua.x; in[5] = ua.y; in[6] = ua.z; in[7] = ua.w;
        in[8] = ub.x; in[9] = ub.y; in[10] = ub.z; in[11] = ub.w;

        float h1[16];
#pragma unroll
        for (int c = 0; c < 16; c++) {
            float s = b1[c];
#pragma unroll
            for (int j = 0; j < 12; j++) s = fmaf(W1[c * 12 + j], in[j], s);
            h1[c] = fmaxf(s, 0.f);
        }
        ln_reg(h1, lg, lb);
        float h2[16];
#pragma unroll
        for (int c = 0; c < 16; c++) {
            float s = b2[c];
#pragma unroll
            for (int j = 0; j < 16; j++) s = fmaf(W2[c * 16 + j], h1[j], s);
            h2[c] = fmaxf(s, 0.f);
        }
        ln_reg(h2, lg, lb);
        float h3[16];
#pragma unroll
        for (int c = 0; c < 16; c++) {
            float s = b3[c];
#pragma unroll
            for (int j = 0; j < 16; j++) s = fmaf(W3[c * 16 + j], h2[j], s);
            h3[c] = fmaxf(s, 0.f);
        }
        ln_reg(h3, lg, lb);
#pragma unroll
        for (int c = 0; c < 16; c++) atomicAdd(&zs[dst * 17 + c], h3[c]);
    }
    __syncthreads();

    // ---- k/v projection for all 100 nodes (q computed on demand in attn) ----
    {
        float wkr[16], wvr[16];
#pragma unroll
        for (int j = 0; j < 16; j++) { wkr[j] = Wk1[lane * 16 + j]; wvr[j] = Wv1[lane * 16 + j]; }
        float bkl = bk1[lane], bvl = bv1[lane];
        for (int base = 0; base < Nn; base += 8) {
            int n = base + w;
            if (n < Nn) {
                float ak = bkl, av = bvl;
#pragma unroll
                for (int j = 0; j < 16; j++) {
                    float zj = zs[n * 17 + j];
                    ak = fmaf(wkr[j], zj, ak);
                    av = fmaf(wvr[j], zj, av);
                }
                size_t o = ((size_t)b * Nn + n) * 64 + lane;
                k1[o] = ak;
                v1[o] = av;
            }
        }
    }
    __syncthreads();   // k1/v1 visible (same CU, L1-coherent)

    // ---- g1 attention at marked nodes (wave per node, online softmax) ----
    {
        int nmk = nmark;
        float wer[8];
#pragma unroll
        for (int j = 0; j < 8; j++) wer[j] = We1[lane * 8 + j];
        float wqr[16];
#pragma unroll
        for (int j = 0; j < 16; j++) wqr[j] = Wq1[lane * 16 + j];
        float bql = bq1[lane];

        for (int li = w; li < nmk; li += 8) {
            int n = list[li];
            float ql = bql;
#pragma unroll
            for (int j = 0; j < 16; j++) ql = fmaf(wqr[j], zs[n * 17 + j], ql);
            int o0 = offl[n], deg = offl[n + 1] - o0;
            const int2* cp = cpair + (size_t)b * Ee + o0;
            const float* kb = k1 + (size_t)b * Nn * 64;
            const float* vb = v1 + (size_t)b * Nn * 64;

            float m = -1e30f, l = 0.f, acc = 0.f;
            int i = 0;
            for (; i + 2 <= deg; i += 2) {
                int2 pA = cp[i], pB = cp[i + 1];
                const float4* eaA = (const float4*)(ea + ((size_t)b * Ee + pA.y) * 8);
                const float4* eaB = (const float4*)(ea + ((size_t)b * Ee + pB.y) * 8);
                float4 a0v = eaA[0], a1v = eaA[1], b0v = eaB[0], b1v = eaB[1];
                float eA = wer[0]*a0v.x + wer[1]*a0v.y + wer[2]*a0v.z + wer[3]*a0v.w
                         + wer[4]*a1v.x + wer[5]*a1v.y + wer[6]*a1v.z + wer[7]*a1v.w;
                float eB = wer[0]*b0v.x + wer[1]*b0v.y + wer[2]*b0v.z + wer[3]*b0v.w
                         + wer[4]*b1v.x + wer[5]*b1v.y + wer[6]*b1v.z + wer[7]*b1v.w;
                float kA = kb[(size_t)pA.x * 64 + lane];
                float kB = kb[(size_t)pB.x * 64 + lane];
                float vA = vb[(size_t)pA.x * 64 + lane];
                float vB = vb[(size_t)pB.x * 64 + lane];
                float tA = ql * (kA + eA);
                float tB = ql * (kB + eB);
                tA += __shfl_xor(tA, 1, 16);  tB += __shfl_xor(tB, 1, 16);
                tA += __shfl_xor(tA, 2, 16);  tB += __shfl_xor(tB, 2, 16);
                tA += __shfl_xor(tA, 4, 16);  tB += __shfl_xor(tB, 4, 16);
                tA += __shfl_xor(tA, 8, 16);  tB += __shfl_xor(tB, 8, 16);
                float lA = tA * 0.25f;
                float lB = tB * 0.25f;
                float nm = fmaxf(m, fmaxf(lA, lB));
                float sc = __expf(m - nm);
                float wA = __expf(lA - nm);
                float wB = __expf(lB - nm);
                acc = acc * sc + wA * (vA + eA) + wB * (vB + eB);
                l   = l * sc + wA + wB;
                m   = nm;
            }
            for (; i < deg; i++) {
                int2 p = cp[i];
                const float4* ea4 = (const float4*)(ea + ((size_t)b * Ee + p.y) * 8);
                float4 u0 = ea4[0], u1 = ea4[1];
                float el = wer[0]*u0.x + wer[1]*u0.y + wer[2]*u0.z + wer[3]*u0.w
                         + wer[4]*u1.x + wer[5]*u1.y + wer[6]*u1.z + wer[7]*u1.w;
                float kl = kb[(size_t)p.x * 64 + lane];
                float tq = ql * (kl + el);
                tq += __shfl_xor(tq, 1, 16);
                tq += __shfl_xor(tq, 2, 16);
                tq += __shfl_xor(tq, 4, 16);
                tq += __shfl_xor(tq, 8, 16);
                float logit = tq * 0.25f;
                float nm = fmaxf(m, logit);
                float sc = __expf(m - nm);
                float wt = __expf(logit - nm);
                float vl = vb[(size_t)p.x * 64 + lane];
                acc = acc * sc + wt * (vl + el);
                l   = l * sc + wt;
                m   = nm;
            }
            float y = (deg > 0) ? (acc / l) : 0.f;
            y += __shfl_xor(y, 16);
            y += __shfl_xor(y, 32);
            y *= 0.25f;
            if (lane < 16) {
                float r = bs1[lane];
#pragma unroll
                for (int j = 0; j < 16; j++) r = fmaf(Ws1[lane * 16 + j], zs[n * 17 + j], r);
                a1s[n * 16 + lane] = y + r;
            }
        }
    }
    __syncthreads();

    // ---- g2 at the agent node (8 waves stride edges, LDS online-softmax merge) ----
    {
        int o0 = offl[an], deg = offl[an + 1] - o0;
        int c0 = lane * 2, c1 = c0 + 1;
        float wk0[16], wk1r[16], wv0[16], wv1r[16], we0[8], we1[8];
#pragma unroll
        for (int j = 0; j < 16; j++) {
            wk0[j] = Wk2[c0 * 16 + j];  wk1r[j] = Wk2[c1 * 16 + j];
            wv0[j] = Wv2[c0 * 16 + j];  wv1r[j] = Wv2[c1 * 16 + j];
        }
#pragma unroll
        for (int j = 0; j < 8; j++) { we0[j] = We2[c0 * 8 + j]; we1[j] = We2[c1 * 8 + j]; }
        float q0 = bq2[c0], q1v = bq2[c1];
#pragma unroll
        for (int j = 0; j < 16; j++) {
            float aj = a1s[an * 16 + j];
            q0  = fmaf(Wq2[c0 * 16 + j], aj, q0);
            q1v = fmaf(Wq2[c1 * 16 + j], aj, q1v);
        }
        const int2* cp = cpair + (size_t)b * Ee + o0;

        float m = -1e30f, l = 0.f, a0 = 0.f, a1c = 0.f;
        for (int i = w; i < deg; i += 8) {
            int2 p = cp[i];
            int srcl = p.x;
            const float4* ea4 = (const float4*)(ea + ((size_t)b * Ee + p.y) * 8);
            float4 u0 = ea4[0], u1 = ea4[1];
            float k0 = bk2[c0], k1e = bk2[c1], vv0 = bv2[c0], vv1 = bv2[c1];
#pragma unroll
            for (int j = 0; j < 16; j++) {
                float aj = a1s[srcl * 16 + j];
                k0  = fmaf(wk0[j],  aj, k0);
                k1e = fmaf(wk1r[j], aj, k1e);
                vv0 = fmaf(wv0[j],  aj, vv0);
                vv1 = fmaf(wv1r[j], aj, vv1);
            }
            float e0 = we0[0]*u0.x + we0[1]*u0.y + we0[2]*u0.z + we0[3]*u0.w
                     + we0[4]*u1.x + we0[5]*u1.y + we0[6]*u1.z + we0[7]*u1.w;
            float e1 = we1[0]*u0.x + we1[1]*u0.y + we1[2]*u0.z + we1[3]*u0.w
                     + we1[4]*u1.x + we1[5]*u1.y + we1[6]*u1.z + we1[7]*u1.w;
            float tq = q0 * (k0 + e0) + q1v * (k1e + e1);
            tq += __shfl_xor(tq, 1, 16);
            tq += __shfl_xor(tq, 2, 16);
            tq += __shfl_xor(tq, 4, 16);
            tq += __shfl_xor(tq, 8, 16);
            float logit = tq * 0.17677669529663687f;   // / sqrt(32)
            float nm = fmaxf(m, logit);
            float sc = __expf(m - nm);
            float wt = __expf(logit - nm);
            a0  = a0 * sc + wt * (vv0 + e0);
            a1c = a1c * sc + wt * (vv1 + e1);
            l   = l * sc + wt;
            m   = nm;
        }
        sm[w][lane] = m; sl[w][lane] = l; sa0[w][lane] = a0; sa1[w][lane] = a1c;
        __syncthreads();
        if (w == 0) {
            float M = sm[0][lane];
#pragma unroll
            for (int ww = 1; ww < 8; ww++) M = fmaxf(M, sm[ww][lane]);
            float L = 0.f, A0 = 0.f, A1 = 0.f;
#pragma unroll
            for (int ww = 0; ww < 8; ww++) {
                float sc = __expf(sm[ww][lane] - M);
                L  += sc * sl[ww][lane];
                A0 += sc * sa0[ww][lane];
                A1 += sc * sa1[ww][lane];
            }
            float y0 = (deg > 0) ? (A0 / L) : 0.f;
            float y1 = (deg > 0) ? (A1 / L) : 0.f;
            y0 += __shfl_xor(y0, 16); y0 += __shfl_xor(y0, 32);
            y1 += __shfl_xor(y1, 16); y1 += __shfl_xor(y1, 32);
            y0 *= 0.25f; y1 *= 0.25f;
            if (lane < 16) {
                int d0 = lane * 2, d1 = d0 + 1;
                float r0 = bs2[d0], r1 = bs2[d1];
#pragma unroll
                for (int j = 0; j < 16; j++) {
                    float aj = a1s[an * 16 + j];
                    r0 = fmaf(Ws2[d0 * 16 + j], aj, r0);
                    r1 = fmaf(Ws2[d1 * 16 + j], aj, r1);
                }
                out[b * 32 + d0] = fmaxf(y0 + r0, 0.f);
                out[b * 32 + d1] = fmaxf(y1 + r1, 0.f);
            }
        }
    }
}

// ---------------- launch ----------------

extern "C" void kernel_launch(void* const* d_in, const int* in_sizes, int n_in,
                              void* d_out, int out_size, void* d_ws, size_t ws_size,
                              hipStream_t stream) {
    (void)in_sizes; (void)n_in; (void)out_size; (void)ws_size;
    const float* nf    = (const float*)d_in[0];
    const int*   ei    = (const int*)d_in[1];
    const float* ea    = (const float*)d_in[2];
    const int*   agent = (const int*)d_in[3];
    const float* ee    = (const float*)d_in[4];
    const float* W1    = (const float*)d_in[5];
    const float* b1    = (const float*)d_in[6];
    const float* W2    = (const float*)d_in[7];
    const float* b2    = (const float*)d_in[8];
    const float* W3    = (const float*)d_in[9];
    const float* b3    = (const float*)d_in[10];
    const float* lg    = (const float*)d_in[11];
    const float* lb    = (const float*)d_in[12];
    const float* g1Wq  = (const float*)d_in[13];
    const float* g1bq  = (const float*)d_in[14];
    const float* g1Wk  = (const float*)d_in[15];
    const float* g1bk  = (const float*)d_in[16];
    const float* g1Wv  = (const float*)d_in[17];
    const float* g1bv  = (const float*)d_in[18];
    const float* g1We  = (const float*)d_in[19];
    const float* g1Ws  = (const float*)d_in[20];
    const float* g1bs  = (const float*)d_in[21];
    const float* g2Wq  = (const float*)d_in[22];
    const float* g2bq  = (const float*)d_in[23];
    const float* g2Wk  = (const float*)d_in[24];
    const float* g2bk  = (const float*)d_in[25];
    const float* g2Wv  = (const float*)d_in[26];
    const float* g2bv  = (const float*)d_in[27];
    const float* g2We  = (const float*)d_in[28];
    const float* g2Ws  = (const float*)d_in[29];
    const float* g2bs  = (const float*)d_in[30];
    float* out = (float*)d_out;

    char* w = (char*)d_ws;
    int2* cpair = (int2*)w; w += (size_t)ETOT * 8;
    float* k1  = (float*)w; w += (size_t)NTOT * 64 * 4;
    float* v1  = (float*)w; w += (size_t)NTOT * 64 * 4;

    k_all<<<dim3(Bb), dim3(NT), 0, stream>>>(
        nf, ei, ea, agent, ee,
        W1, b1, W2, b2, W3, b3, lg, lb,
        g1Wq, g1bq, g1Wk, g1bk, g1Wv, g1bv, g1We, g1Ws, g1bs,
        g2Wq, g2bq, g2Wk, g2bk, g2Wv, g2bv, g2We, g2Ws, g2bs,
        cpair, k1, v1, out);
}